// Round 8
// baseline (181.060 us; speedup 1.0000x reference)
//
#include <hip/hip_runtime.h>
#include <math.h>

#define BB 8
#define CC 64
#define OO 64
#define HH 128
#define WW 128
#define HW (HH*WW)              // 16384
#define NPIX (BB*HW)            // 131072

typedef __bf16 bf16x8 __attribute__((ext_vector_type(8)));
typedef float floatx4 __attribute__((ext_vector_type(4)));
typedef float f32x2  __attribute__((ext_vector_type(2)));
typedef unsigned short ushort_t;

// Workspace layout (bytes):
//  wt : bf16 [64][576]  (o, tap*64+c)      73728
//  wb : bf16 [32][576]  (o27pad, tap*64+c) 36864
#define WT_BYTES  73728

__device__ __forceinline__ unsigned short f2b(float f) {
    unsigned u = __float_as_uint(f);
    u += 0x7fffu + ((u >> 16) & 1u);       // round-to-nearest-even
    return (unsigned short)(u >> 16);
}

// ---------------------------------------------------------------------------
// Kernel 1: weight repack to bf16
// ---------------------------------------------------------------------------
__global__ __launch_bounds__(256) void repack_kernel(
    const float* __restrict__ wm, const float* __restrict__ woff,
    const float* __restrict__ wmask, ushort_t* __restrict__ wt,
    ushort_t* __restrict__ wb)
{
    int i = blockIdx.x * 256 + threadIdx.x;
    if (i < 36864) {
        int o = i / 576, k = i % 576, tap = k >> 6, c = k & 63;
        wt[i] = f2b(wm[o*576 + c*9 + tap]);
    }
    int j = i - 36864;
    if (j >= 0 && j < 18432) {
        int o = j / 576, k = j % 576, tap = k >> 6, c = k & 63;
        float v = 0.f;
        if (o < 18)      v = woff[o*576 + c*9 + tap];
        else if (o < 27) v = wmask[(o-18)*576 + c*9 + tap];
        wb[j] = f2b(v);
    }
}

// ---------------------------------------------------------------------------
// Kernel 2 (FUSED, reads NCHW x directly): per 8x8 tile:
//   1. stage 12x12 halo window of x (NCHW fp32 -> bf16 [px][ch]) into LDS;
//      per-thread channel-loop does the transpose in-register
//   2. conv3x3 -> 18 offsets + 9 sigmoid masks via MFMA -> om_lds (no HBM)
//   3. deformable bilinear sampling from LDS (global NCHW fallback for
//      corners outside the window), pipelined one tap ahead of
//   4. bf16 MFMA GEMM (M=64 px, N=64, K=576) -> out
// LDS: win 20736 + samp 9216 + om 7424 = 37376 B -> 4 blocks/CU
// ---------------------------------------------------------------------------
#define WR 12                       // window rows/cols (8 + 2*2 halo)
#define WSTRIDE 72                  // shorts per window pixel (64 + pad)
#define OMS 29                      // om_lds floats per pixel (28 + pad)

__global__ __launch_bounds__(256) void fused_kernel(
    const float* __restrict__ x, const ushort_t* __restrict__ wb,
    const float* __restrict__ boff, const float* __restrict__ bmsk,
    const ushort_t* __restrict__ wt, float* __restrict__ out)
{
    __shared__ ushort_t win[WR*WR*WSTRIDE];   // 20736 B
    __shared__ ushort_t samp[64*72];          //  9216 B
    __shared__ float    om_lds[64*OMS];       //  7424 B

    int t = threadIdx.x;
    int lane = t & 63, wv = t >> 6;
    int bid = blockIdx.x;
    int b  = bid >> 8;
    int th = (bid >> 4) & 15;
    int tw = bid & 15;
    int h0 = th * 8, w0 = tw * 8;
    const float* xb = x + ((size_t)b*CC << 14);   // batch base (NCHW)

    // ---- 1. stage 12x12 window: NCHW fp32 -> bf16 [px][ch] ----
    // thread t: position (t&127), channel half (t>>7); 16 extra positions
    // (128..143) by threads with (t&127)<16.
    {
        int half = t >> 7;            // 0: ch 0..31, 1: ch 32..63
        int p    = t & 127;
        #pragma unroll
        for (int rep = 0; rep < 2; ++rep) {
            int pos = rep ? (128 + p) : p;
            if (rep && p >= 16) break;
            int r = pos / WR, col = pos - r*WR;
            int y = h0 + r - 2, xw = w0 + col - 2;
            bool valid = ((unsigned)y < (unsigned)HH) &&
                         ((unsigned)xw < (unsigned)WW);
            const float* xp = xb + ((size_t)(half*32) << 14) + (y << 7) + xw;
            ushort_t* wp = win + pos*WSTRIDE + half*32;
            #pragma unroll
            for (int g = 0; g < 4; ++g) {          // 8 channels per b128
                unsigned uu[4];
                #pragma unroll
                for (int q = 0; q < 4; ++q) {
                    int c = g*8 + 2*q;
                    float lo = valid ? xp[(size_t)c << 14]       : 0.f;
                    float hi = valid ? xp[(size_t)(c+1) << 14]   : 0.f;
                    uu[q] = (unsigned)f2b(lo) | ((unsigned)f2b(hi) << 16);
                }
                *(uint4*)(wp + g*8) = make_uint4(uu[0], uu[1], uu[2], uu[3]);
            }
        }
    }
    __syncthreads();

    int n = lane & 15, quad = lane >> 4;

    // ---- 2. conv27: wave wv owns M-tile of 16 px, N=32, K=576 ----
    {
        const ushort_t* wb0 = wb + n*576;
        const ushort_t* wb1 = wb + (16 + n)*576;
        floatx4 acc0 = {0.f,0.f,0.f,0.f}, acc1 = {0.f,0.f,0.f,0.f};
        int trow = wv*2 + (n >> 3);          // tile row of pixel m=n
        int tcol = n & 7;

        #pragma unroll
        for (int s = 0; s < 18; ++s) {
            int tap  = s >> 1;
            int tr   = tap / 3, tc = tap % 3;
            int coff = (s & 1)*32 + quad*8;
            int kk = tap*64 + coff;
            bf16x8 b0 = *(const bf16x8*)(wb0 + kk);
            bf16x8 b1 = *(const bf16x8*)(wb1 + kk);
            bf16x8 a = *(const bf16x8*)(win +
                ((trow + tr + 1)*WR + (tcol + tc + 1))*WSTRIDE + coff);
            acc0 = __builtin_amdgcn_mfma_f32_16x16x32_bf16(a, b0, acc0, 0, 0, 0);
            acc1 = __builtin_amdgcn_mfma_f32_16x16x32_bf16(a, b1, acc1, 0, 0, 0);
        }

        #pragma unroll
        for (int r = 0; r < 4; ++r) {
            int p = wv*16 + quad*4 + r;
            float* dst = om_lds + p*OMS;
            dst[n] = acc0[r] + boff[n];
            int o1 = 16 + n;
            if (o1 < 18) {
                dst[o1] = acc1[r] + boff[o1];
            } else if (o1 < 27) {
                float z = acc1[r] + bmsk[o1 - 18];
                dst[o1] = 1.f / (1.f + expf(-z));
            }
        }
    }
    __syncthreads();

    // ---- 3+4. deform: phase-A role 4 thr/px (16 ch each), pipelined ----
    int pa = t >> 2, cg = t & 3;
    int ph = pa >> 3, pw = pa & 7;
    int h_a = h0 + ph, w_a = w0 + pw;
    const float* omp = om_lds + pa*OMS;

    floatx4 acc[4];
    #pragma unroll
    for (int i = 0; i < 4; ++i) acc[i] = (floatx4){0.f,0.f,0.f,0.f};
    const ushort_t* wrow = wt + (wv*16 + n)*576;

    // phase A for tap k: reads only win/om_lds (stable) -> no samp dependence
    auto computeA = [&](int k, f32x2* v2) {
        int kr = k / 3, kc = k - kr*3;
        float dy = omp[2*k], dx = omp[2*k + 1], m = omp[18 + k];
        float py = (float)(h_a + kr - 1) + dy;
        float px = (float)(w_a + kc - 1) + dx;
        float y0f = floorf(py), x0f = floorf(px);
        float ly = py - y0f, lx = px - x0f;
        int y0 = (int)y0f, x0 = (int)x0f, y1 = y0 + 1, x1 = x0 + 1;
        float vy0 = ((unsigned)y0 < (unsigned)HH) ? 1.f : 0.f;
        float vy1 = ((unsigned)y1 < (unsigned)HH) ? 1.f : 0.f;
        float vx0 = ((unsigned)x0 < (unsigned)WW) ? 1.f : 0.f;
        float vx1 = ((unsigned)x1 < (unsigned)WW) ? 1.f : 0.f;

        float cw[4] = { (1.f-ly)*(1.f-lx)*vy0*vx0*m,
                        (1.f-ly)*lx      *vy0*vx1*m,
                        ly*(1.f-lx)      *vy1*vx0*m,
                        ly*lx            *vy1*vx1*m };
        int ys[4] = { y0, y0, y1, y1 };
        int xs[4] = { x0, x1, x0, x1 };

        #pragma unroll
        for (int i = 0; i < 8; ++i) v2[i] = (f32x2){0.f, 0.f};

        #pragma unroll
        for (int cn = 0; cn < 4; ++cn) {
            int yc = min(max(ys[cn], 0), HH-1);
            int xc = min(max(xs[cn], 0), WW-1);
            int wy = yc - h0 + 2, wx = xc - w0 + 2;
            float wg = cw[cn];
            if ((unsigned)wy < (unsigned)WR && (unsigned)wx < (unsigned)WR) {
                const uint4* cp = (const uint4*)(win + (wy*WR + wx)*WSTRIDE + cg*16);
                uint4 q0 = cp[0], q1 = cp[1];
                unsigned d[8] = { q0.x, q0.y, q0.z, q0.w, q1.x, q1.y, q1.z, q1.w };
                #pragma unroll
                for (int j = 0; j < 8; ++j) {
                    f32x2 e;
                    e.x = __uint_as_float(d[j] << 16);
                    e.y = __uint_as_float(d[j] & 0xffff0000u);
                    v2[j] += e * wg;            // -> v_pk_fma_f32
                }
            } else {      // corner outside staged window: NCHW global reads
                const float* cp = xb + ((size_t)(cg*16) << 14) + (yc << 7) + xc;
                #pragma unroll
                for (int j = 0; j < 8; ++j) {
                    f32x2 e;
                    e.x = cp[(size_t)(2*j)   << 14];
                    e.y = cp[(size_t)(2*j+1) << 14];
                    v2[j] += e * wg;
                }
            }
        }
    };

    f32x2 v2[8];
    computeA(0, v2);

    for (int k = 0; k < 9; ++k) {
        // write samp <- v2
        {
            unsigned uu[8];
            #pragma unroll
            for (int j = 0; j < 8; ++j)
                uu[j] = (unsigned)f2b(v2[j].x) | ((unsigned)f2b(v2[j].y) << 16);
            uint4* dst = (uint4*)(samp + pa*72 + cg*16);
            dst[0] = make_uint4(uu[0], uu[1], uu[2], uu[3]);
            dst[1] = make_uint4(uu[4], uu[5], uu[6], uu[7]);
        }
        __syncthreads();   // publish samp for tap k

        // phase B (MFMA on samp) + phase A for tap k+1 — independent pipes
        #pragma unroll
        for (int half = 0; half < 2; ++half) {
            bf16x8 bfrag = *(const bf16x8*)(wrow + k*64 + half*32 + quad*8);
            #pragma unroll
            for (int mt = 0; mt < 4; ++mt) {
                bf16x8 afrag = *(const bf16x8*)(samp + (mt*16 + n)*72 + half*32 + quad*8);
                acc[mt] = __builtin_amdgcn_mfma_f32_16x16x32_bf16(afrag, bfrag, acc[mt], 0, 0, 0);
            }
        }
        if (k < 8) computeA(k + 1, v2);

        __syncthreads();   // all reads of samp done before next write
    }

    // store: out[b][o][h][w], o = wv*16 + n
    float* op = out + ((size_t)b*OO + (wv*16 + n))*HW;
    #pragma unroll
    for (int mt = 0; mt < 4; ++mt) {
        int row = h0 + mt*2 + (quad >> 1);
        int col = w0 + (quad & 1)*4;
        float4 st = make_float4(acc[mt][0], acc[mt][1], acc[mt][2], acc[mt][3]);
        *(float4*)(op + row*WW + col) = st;
    }
}

// ---------------------------------------------------------------------------
extern "C" void kernel_launch(void* const* d_in, const int* in_sizes, int n_in,
                              void* d_out, int out_size, void* d_ws, size_t ws_size,
                              hipStream_t stream)
{
    const float* x      = (const float*)d_in[0];
    const float* w_main = (const float*)d_in[1];
    const float* w_off  = (const float*)d_in[2];
    const float* b_off  = (const float*)d_in[3];
    const float* w_msk  = (const float*)d_in[4];
    const float* b_msk  = (const float*)d_in[5];
    float* out = (float*)d_out;

    unsigned char* ws = (unsigned char*)d_ws;
    ushort_t* wt = (ushort_t*)ws;
    ushort_t* wb = (ushort_t*)(ws + WT_BYTES);

    repack_kernel<<<(36864 + 18432 + 255)/256, 256, 0, stream>>>(
        w_main, w_off, w_msk, wt, wb);

    fused_kernel<<<NPIX/64, 256, 0, stream>>>(x, wb, b_off, b_msk, wt, out);
}